// Round 11
// baseline (453.299 us; speedup 1.0000x reference)
//
#include <hip/hip_runtime.h>

#define SEQ    256
#define BATCHN 2048
#define NIN    64
#define H      128
#define NOUT   64
#define TOUT   128
#define BT     16     // batch rows per block -> 128 blocks
#define ASTR   200    // LDS A-row stride in halfs (192 + 8 pad)
#define TCH    16     // decoder steps buffered before a coalesced flush
#define WSTR   136    // W'-prep LDS row stride in halfs (128 + 8)

using half8 = _Float16 __attribute__((ext_vector_type(8)));
using f32x4 = float    __attribute__((ext_vector_type(4)));

__device__ __forceinline__ float sigf(float v) {
    return __builtin_amdgcn_rcpf(1.f + __expf(-v));
}
__device__ __forceinline__ float tanhfast(float v) {
    return 1.f - 2.f * __builtin_amdgcn_rcpf(1.f + __expf(2.f * v));
}

__device__ __forceinline__ half8 ldfrag8(const float* __restrict__ p) {
    half8 r;
#pragma unroll
    for (int e = 0; e < 8; ++e) r[e] = (_Float16)p[e];
    return r;
}

// Round 11 = round-5 skeleton (best measured: 397 us) + HW-validated fused decoder.
// Encoder: r5 verbatim — 1 barrier/step, x prefetched one full step ahead,
// serial per-r sigf/tanhfast activations, single 6-deep MFMA chains.
// Decoder: gates_k = W'.h_{k-1} + b' with W' = dWih@oW + dWhh (y eliminated from
// the recurrence chain); y_k = oW.h_k + ob computed off-path by waves 0-3.
// MFMA 16x16x32 f16 maps (HW-verified r2-r3): A row = lane&15, B col = lane&15,
// D row = 4*(lane>>4)+r, D col = lane&15.
__global__ __launch_bounds__(512, 2) void seq2seq_fused(
    const float* __restrict__ x,
    const float* __restrict__ eWih, const float* __restrict__ eWhh, const float* __restrict__ eb,
    const float* __restrict__ dWih, const float* __restrict__ dWhh, const float* __restrict__ db,
    const float* __restrict__ oW,   const float* __restrict__ obv,
    float* __restrict__ out)
{
    __shared__ __align__(16) _Float16 als[2][BT][ASTR];  // [b][k], k: 0..63 = x, 64..191 = h
    __shared__ __align__(16) _Float16 ybuf[TCH][BT][68]; // y staging; ALIASED as W'-prep scratch

    const int tid  = threadIdx.x;
    const int lane = tid & 63;
    const int w    = tid >> 6;
    const int jl   = lane & 15;
    const int lg   = lane >> 4;
    const int b0   = blockIdx.x * BT;

    float c[4] = {0.f, 0.f, 0.f, 0.f};  // cell state, rows 4*lg+r, col 16w+jl

    // ---------------- encoder weights -> resident VGPR fragments ----------------
    half8 wf[4][6];
    float bq[4];
#pragma unroll
    for (int q = 0; q < 4; ++q) {
        const int j = q * H + w * 16 + jl;
#pragma unroll
        for (int kc = 0; kc < 2; ++kc)
            wf[q][kc] = ldfrag8(eWih + j * NIN + kc * 32 + lg * 8);
#pragma unroll
        for (int kc = 2; kc < 6; ++kc)
            wf[q][kc] = ldfrag8(eWhh + j * H + (kc - 2) * 32 + lg * 8);
        bq[q] = eb[j];
    }

    for (int i = tid; i < 2 * BT * ASTR; i += 512) ((_Float16*)als)[i] = (_Float16)0.f;
    __syncthreads();
    const int xi = tid >> 5, xn = (tid & 31) * 2;
    {
        const float2 xv = *(const float2*)(x + (b0 + xi) * NIN + xn);
        als[0][xi][xn]     = (_Float16)xv.x;
        als[0][xi][xn + 1] = (_Float16)xv.y;
    }
    __syncthreads();

    // ---------------- encoder: 256 steps, 1 barrier/step (r5 verbatim) ----------------
    for (int t = 0; t < SEQ; ++t) {
        const int cur = t & 1, nxt = cur ^ 1;

        float2 xv = make_float2(0.f, 0.f);
        if (t + 1 < SEQ)
            xv = *(const float2*)(x + ((size_t)(t + 1) * BATCHN + b0 + xi) * NIN + xn);

        half8 af[6];
#pragma unroll
        for (int kc = 0; kc < 6; ++kc)
            af[kc] = *(const half8*)&als[cur][jl][kc * 32 + lg * 8];

        f32x4 ac[4];
#pragma unroll
        for (int q = 0; q < 4; ++q) {
            f32x4 a = {bq[q], bq[q], bq[q], bq[q]};
#pragma unroll
            for (int kc = 0; kc < 6; ++kc)
                a = __builtin_amdgcn_mfma_f32_16x16x32_f16(af[kc], wf[q][kc], a, 0, 0, 0);
            ac[q] = a;
        }

#pragma unroll
        for (int r = 0; r < 4; ++r) {
            const float ig = sigf(ac[0][r]);
            const float fg = sigf(ac[1][r]);
            const float gg = tanhfast(ac[2][r]);
            const float og = sigf(ac[3][r]);
            c[r] = fg * c[r] + ig * gg;
            const float hv = og * tanhfast(c[r]);
            als[nxt][lg * 4 + r][NIN + w * 16 + jl] = (_Float16)hv;
        }
        als[nxt][xi][xn]     = (_Float16)xv.x;
        als[nxt][xi][xn + 1] = (_Float16)xv.y;
        __syncthreads();
    }
    // h_enc in als[0]

    // ---------------- decoder step k=0: gates = dWhh . h_enc + db  (x0 = 0) ----------------
#pragma unroll
    for (int q = 0; q < 4; ++q) {
        const int j = q * H + w * 16 + jl;
#pragma unroll
        for (int kc = 0; kc < 4; ++kc)
            wf[q][kc] = ldfrag8(dWhh + j * H + kc * 32 + lg * 8);
        bq[q] = db[j];
    }
    {
        half8 af[4];
#pragma unroll
        for (int kc = 0; kc < 4; ++kc)
            af[kc] = *(const half8*)&als[0][jl][NIN + kc * 32 + lg * 8];
        f32x4 ac[4];
#pragma unroll
        for (int q = 0; q < 4; ++q) {
            f32x4 a = {bq[q], bq[q], bq[q], bq[q]};
#pragma unroll
            for (int kc = 0; kc < 4; ++kc)
                a = __builtin_amdgcn_mfma_f32_16x16x32_f16(af[kc], wf[q][kc], a, 0, 0, 0);
            ac[q] = a;
        }
#pragma unroll
        for (int r = 0; r < 4; ++r) {
            const float ig = sigf(ac[0][r]);
            const float fg = sigf(ac[1][r]);
            const float gg = tanhfast(ac[2][r]);
            const float og = sigf(ac[3][r]);
            c[r] = fg * c[r] + ig * gg;
            const float hv = og * tanhfast(c[r]);
            als[1][lg * 4 + r][NIN + w * 16 + jl] = (_Float16)hv;  // h_0 -> als[1]
        }
        __syncthreads();
    }

    // ---------------- y-GEMM weights (waves 0-3) ----------------
    half8 of[4];
    float oB = 0.f;
    if (w < 4) {
        const int j = w * 16 + jl;
#pragma unroll
        for (int kc = 0; kc < 4; ++kc)
            of[kc] = ldfrag8(oW + j * H + kc * 32 + lg * 8);
        oB = obv[j];
    }

    // ---------------- W' prep: wf := frags of (dWih@oW + dWhh); bq := db + dWih@ob ----------
    // q fully unrolled so wf stays register-resident (r9 lesson: runtime q -> scratch spill).
    {
        _Float16* mybuf = ((_Float16*)ybuf) + (size_t)w * 16 * WSTR;
#pragma unroll
        for (int q = 0; q < 4; ++q) {
            const int jb = q * H + w * 16;           // wave's 16-row j-tile base
            half8 afp[2];
#pragma unroll
            for (int k2 = 0; k2 < 2; ++k2)
                afp[k2] = ldfrag8(dWih + (jb + jl) * NIN + k2 * 32 + lg * 8);
#pragma unroll 1
            for (int nt = 0; nt < 8; ++nt) {
                half8 bf0, bf1;                      // oW[m][nt*16+jl]
#pragma unroll
                for (int e = 0; e < 8; ++e) {
                    bf0[e] = (_Float16)oW[(lg * 8 + e) * H + nt * 16 + jl];
                    bf1[e] = (_Float16)oW[(32 + lg * 8 + e) * H + nt * 16 + jl];
                }
                f32x4 acc;
#pragma unroll
                for (int r = 0; r < 4; ++r)
                    acc[r] = dWhh[(jb + lg * 4 + r) * H + nt * 16 + jl];
                acc = __builtin_amdgcn_mfma_f32_16x16x32_f16(afp[0], bf0, acc, 0, 0, 0);
                acc = __builtin_amdgcn_mfma_f32_16x16x32_f16(afp[1], bf1, acc, 0, 0, 0);
#pragma unroll
                for (int r = 0; r < 4; ++r)
                    mybuf[(lg * 4 + r) * WSTR + nt * 16 + jl] = (_Float16)acc[r];
            }
            __syncthreads();                          // wave's W'(q) tile complete in LDS
#pragma unroll
            for (int kc = 0; kc < 4; ++kc)
                wf[q][kc] = *(const half8*)&mybuf[jl * WSTR + kc * 32 + lg * 8];
            float s = db[jb + jl];
            for (int m = 0; m < NIN; ++m) s += dWih[(jb + jl) * NIN + m] * obv[m];
            bq[q] = s;
            __syncthreads();                          // frags read before next q overwrites
        }
    }

    // ---------------- decoder steady loop: i = 1..128, 1 barrier/step ----------------
    for (int i = 1; i <= TOUT; ++i) {
        const int cur = i & 1, nxt = cur ^ 1;

        half8 af[4];
#pragma unroll
        for (int kc = 0; kc < 4; ++kc)
            af[kc] = *(const half8*)&als[cur][jl][NIN + kc * 32 + lg * 8];

        if (w < 4) {   // y_{i-1} = oW . h_{i-1} + ob  (off the recurrence path)
            f32x4 ya = {oB, oB, oB, oB};
#pragma unroll
            for (int kc = 0; kc < 4; ++kc)
                ya = __builtin_amdgcn_mfma_f32_16x16x32_f16(af[kc], of[kc], ya, 0, 0, 0);
            const int tt = (i - 1) & (TCH - 1);
            const int j = w * 16 + jl;
#pragma unroll
            for (int r = 0; r < 4; ++r)
                ybuf[tt][lg * 4 + r][j] = (_Float16)ya[r];
        }

        if (i < TOUT) {
            f32x4 ac[4];
#pragma unroll
            for (int q = 0; q < 4; ++q) {
                f32x4 a = {bq[q], bq[q], bq[q], bq[q]};
#pragma unroll
                for (int kc = 0; kc < 4; ++kc)
                    a = __builtin_amdgcn_mfma_f32_16x16x32_f16(af[kc], wf[q][kc], a, 0, 0, 0);
                ac[q] = a;
            }
#pragma unroll
            for (int r = 0; r < 4; ++r) {
                const float ig = sigf(ac[0][r]);
                const float fg = sigf(ac[1][r]);
                const float gg = tanhfast(ac[2][r]);
                const float og = sigf(ac[3][r]);
                c[r] = fg * c[r] + ig * gg;
                const float hv = og * tanhfast(c[r]);
                als[nxt][lg * 4 + r][NIN + w * 16 + jl] = (_Float16)hv;
            }
        }
        __syncthreads();   // h_i + ybuf visible

        if ((i & (TCH - 1)) == 0) {   // i = 16,32,...,128: flush y[i-16 .. i-1]
            const int t0 = i - TCH;
#pragma unroll
            for (int it = 0; it < 8; ++it) {
                const int slot = it * 512 + tid;   // 0..4095
                const int pair = slot >> 2;        // (row,j): 0..1023
                const int tq   = slot & 3;
                const int row  = pair >> 6;
                const int j    = pair & 63;
                float4 v;
                v.x = (float)ybuf[tq * 4 + 0][row][j];
                v.y = (float)ybuf[tq * 4 + 1][row][j];
                v.z = (float)ybuf[tq * 4 + 2][row][j];
                v.w = (float)ybuf[tq * 4 + 3][row][j];
                *(float4*)(out + ((size_t)(b0 + row) * NOUT + j) * TOUT + t0 + tq * 4) = v;
            }
            __syncthreads();   // flush done before next iter's ybuf writes (WAR)
        }
    }
}

extern "C" void kernel_launch(void* const* d_in, const int* in_sizes, int n_in,
                              void* d_out, int out_size, void* d_ws, size_t ws_size,
                              hipStream_t stream) {
    (void)in_sizes; (void)n_in; (void)out_size; (void)d_ws; (void)ws_size;
    const float* x    = (const float*)d_in[0];
    const float* eWih = (const float*)d_in[1];
    const float* eWhh = (const float*)d_in[2];
    const float* eb   = (const float*)d_in[3];
    const float* dWih = (const float*)d_in[4];
    const float* dWhh = (const float*)d_in[5];
    const float* db   = (const float*)d_in[6];
    const float* oW   = (const float*)d_in[7];
    const float* ob   = (const float*)d_in[8];

    seq2seq_fused<<<BATCHN / BT, 512, 0, stream>>>(
        x, eWih, eWhh, eb, dWih, dWhh, db, oW, ob, (float*)d_out);
}

// Round 12
// 436.458 us; speedup vs baseline: 1.0386x; 1.0386x over previous
//
#include <hip/hip_runtime.h>

#define SEQ    256
#define BATCHN 2048
#define NIN    64
#define H      128
#define NOUT   64
#define TOUT   128
#define BT     16     // batch rows per block -> 128 blocks
#define ASTR   200    // LDS A-row stride in halfs (192 + 8 pad)
#define TCH    16     // decoder steps buffered before a coalesced flush

using half8 = _Float16 __attribute__((ext_vector_type(8)));
using f32x4 = float    __attribute__((ext_vector_type(4)));

// d_ws layout (bytes), fully rewritten every call:
//   [      0,  131072)  Wp  : f16 [512][128]   W' = dWih@oW + dWhh
//   [ 131072,  133120)  bp  : f32 [512]        b' = db + dWih@ob
//   [ 262144,  786432)  hws : f16 [2048][128]  encoder final h
//   [ 786432, 1835008)  cws : f32 [2048][128]  encoder final c

__device__ __forceinline__ float sigf(float v) {
    return __builtin_amdgcn_rcpf(1.f + __expf(-v));
}
__device__ __forceinline__ float tanhfast(float v) {
    return 1.f - 2.f * __builtin_amdgcn_rcpf(1.f + __expf(2.f * v));
}
__device__ __forceinline__ half8 ldfrag8(const float* __restrict__ p) {
    half8 r;
#pragma unroll
    for (int e = 0; e < 8; ++e) r[e] = (_Float16)p[e];
    return r;
}

// ---------------- kernel 1: W', b' prep (runs once, ~5 us) ----------------
__global__ __launch_bounds__(512) void prep_wp(
    const float* __restrict__ dWih, const float* __restrict__ dWhh, const float* __restrict__ db,
    const float* __restrict__ oW,   const float* __restrict__ obv,
    _Float16* __restrict__ Wp, float* __restrict__ bp)
{
    const int b = blockIdx.x;
    if (b < 128) {                       // W'[j][n] = dWhh[j][n] + sum_m dWih[j][m]*oW[m][n]
        const int idx = b * 512 + (int)threadIdx.x;   // 128*512 = 65536 = 512*128
        const int j = idx >> 7, n = idx & 127;
        float s = dWhh[j * H + n];
        const float* wr = dWih + j * NIN;
#pragma unroll 8
        for (int m = 0; m < NIN; ++m) s += wr[m] * oW[m * H + n];
        Wp[idx] = (_Float16)s;
    } else {                             // b'[j] = db[j] + sum_m dWih[j][m]*ob[m]
        const int j = (int)threadIdx.x;
        float s = db[j];
        const float* wr = dWih + j * NIN;
        for (int m = 0; m < NIN; ++m) s += wr[m] * obv[m];
        bp[j] = s;
    }
}

// ---------------- kernel 2: encoder (r5 verbatim) + h/c writeback ----------------
__global__ __launch_bounds__(512, 2) void enc_kernel(
    const float* __restrict__ x,
    const float* __restrict__ eWih, const float* __restrict__ eWhh, const float* __restrict__ eb,
    _Float16* __restrict__ hws, float* __restrict__ cws)
{
    __shared__ __align__(16) _Float16 als[2][BT][ASTR];

    const int tid  = threadIdx.x;
    const int lane = tid & 63;
    const int w    = tid >> 6;
    const int jl   = lane & 15;
    const int lg   = lane >> 4;
    const int b0   = blockIdx.x * BT;

    half8 wf[4][6];
    float bq[4];
#pragma unroll
    for (int q = 0; q < 4; ++q) {
        const int j = q * H + w * 16 + jl;
#pragma unroll
        for (int kc = 0; kc < 2; ++kc)
            wf[q][kc] = ldfrag8(eWih + j * NIN + kc * 32 + lg * 8);
#pragma unroll
        for (int kc = 2; kc < 6; ++kc)
            wf[q][kc] = ldfrag8(eWhh + j * H + (kc - 2) * 32 + lg * 8);
        bq[q] = eb[j];
    }

    float c[4] = {0.f, 0.f, 0.f, 0.f};

    for (int i = tid; i < 2 * BT * ASTR; i += 512) ((_Float16*)als)[i] = (_Float16)0.f;
    __syncthreads();
    const int xi = tid >> 5, xn = (tid & 31) * 2;
    {
        const float2 xv = *(const float2*)(x + (b0 + xi) * NIN + xn);
        als[0][xi][xn]     = (_Float16)xv.x;
        als[0][xi][xn + 1] = (_Float16)xv.y;
    }
    __syncthreads();

    for (int t = 0; t < SEQ; ++t) {
        const int cur = t & 1, nxt = cur ^ 1;

        float2 xv = make_float2(0.f, 0.f);
        if (t + 1 < SEQ)
            xv = *(const float2*)(x + ((size_t)(t + 1) * BATCHN + b0 + xi) * NIN + xn);

        half8 af[6];
#pragma unroll
        for (int kc = 0; kc < 6; ++kc)
            af[kc] = *(const half8*)&als[cur][jl][kc * 32 + lg * 8];

        f32x4 ac[4];
#pragma unroll
        for (int q = 0; q < 4; ++q) {
            f32x4 a = {bq[q], bq[q], bq[q], bq[q]};
#pragma unroll
            for (int kc = 0; kc < 6; ++kc)
                a = __builtin_amdgcn_mfma_f32_16x16x32_f16(af[kc], wf[q][kc], a, 0, 0, 0);
            ac[q] = a;
        }

#pragma unroll
        for (int r = 0; r < 4; ++r) {
            const float ig = sigf(ac[0][r]);
            const float fg = sigf(ac[1][r]);
            const float gg = tanhfast(ac[2][r]);
            const float og = sigf(ac[3][r]);
            c[r] = fg * c[r] + ig * gg;
            const float hv = og * tanhfast(c[r]);
            als[nxt][lg * 4 + r][NIN + w * 16 + jl] = (_Float16)hv;
        }
        als[nxt][xi][xn]     = (_Float16)xv.x;
        als[nxt][xi][xn + 1] = (_Float16)xv.y;
        __syncthreads();
    }
    // h_enc in als[0] (t=255: nxt=0); write h (f16) and c (f32) to workspace
#pragma unroll
    for (int k = 0; k < 4; ++k) {
        const int idx = tid + k * 512;           // 0..2047 -> (row, n)
        const int row = idx >> 7, n = idx & 127;
        hws[(size_t)(b0 + row) * H + n] = als[0][row][NIN + n];
    }
#pragma unroll
    for (int r = 0; r < 4; ++r)
        cws[(size_t)(b0 + lg * 4 + r) * H + w * 16 + jl] = c[r];
}

// ---------------- kernel 3: fused decoder (r11 steady loop, isolated) ----------------
__global__ __launch_bounds__(512, 2) void dec_kernel(
    const float* __restrict__ dWhh, const float* __restrict__ db,
    const float* __restrict__ oW,   const float* __restrict__ obv,
    const _Float16* __restrict__ Wp, const float* __restrict__ bp,
    const _Float16* __restrict__ hws, const float* __restrict__ cws,
    float* __restrict__ out)
{
    __shared__ __align__(16) _Float16 als[2][BT][ASTR];
    __shared__ __align__(16) _Float16 ybuf[TCH][BT][68];

    const int tid  = threadIdx.x;
    const int lane = tid & 63;
    const int w    = tid >> 6;
    const int jl   = lane & 15;
    const int lg   = lane >> 4;
    const int b0   = blockIdx.x * BT;

    // stage h_enc -> als[0] h-region; load c
#pragma unroll
    for (int k = 0; k < 4; ++k) {
        const int idx = tid + k * 512;
        const int row = idx >> 7, n = idx & 127;
        als[0][row][NIN + n] = hws[(size_t)(b0 + row) * H + n];
    }
    float c[4];
#pragma unroll
    for (int r = 0; r < 4; ++r)
        c[r] = cws[(size_t)(b0 + lg * 4 + r) * H + w * 16 + jl];

    // step 0 weights: dWhh, db (x0 = 0)
    half8 wf[4][4];
    float bq[4];
#pragma unroll
    for (int q = 0; q < 4; ++q) {
        const int j = q * H + w * 16 + jl;
#pragma unroll
        for (int kc = 0; kc < 4; ++kc)
            wf[q][kc] = ldfrag8(dWhh + j * H + kc * 32 + lg * 8);
        bq[q] = db[j];
    }
    half8 of[4];
    float oB = 0.f;
    if (w < 4) {
        const int j = w * 16 + jl;
#pragma unroll
        for (int kc = 0; kc < 4; ++kc)
            of[kc] = ldfrag8(oW + j * H + kc * 32 + lg * 8);
        oB = obv[j];
    }
    __syncthreads();

    // decoder step 0: gates = dWhh.h_enc + db -> h_0 -> als[1]
    {
        half8 af[4];
#pragma unroll
        for (int kc = 0; kc < 4; ++kc)
            af[kc] = *(const half8*)&als[0][jl][NIN + kc * 32 + lg * 8];
        f32x4 ac[4];
#pragma unroll
        for (int q = 0; q < 4; ++q) {
            f32x4 a = {bq[q], bq[q], bq[q], bq[q]};
#pragma unroll
            for (int kc = 0; kc < 4; ++kc)
                a = __builtin_amdgcn_mfma_f32_16x16x32_f16(af[kc], wf[q][kc], a, 0, 0, 0);
            ac[q] = a;
        }
#pragma unroll
        for (int r = 0; r < 4; ++r) {
            const float ig = sigf(ac[0][r]);
            const float fg = sigf(ac[1][r]);
            const float gg = tanhfast(ac[2][r]);
            const float og = sigf(ac[3][r]);
            c[r] = fg * c[r] + ig * gg;
            const float hv = og * tanhfast(c[r]);
            als[1][lg * 4 + r][NIN + w * 16 + jl] = (_Float16)hv;
        }
    }

    // swap in W', b' (from prep kernel; no in-block prep)
#pragma unroll
    for (int q = 0; q < 4; ++q) {
        const int j = q * H + w * 16 + jl;
#pragma unroll
        for (int kc = 0; kc < 4; ++kc)
            wf[q][kc] = *(const half8*)&Wp[(size_t)j * H + kc * 32 + lg * 8];
        bq[q] = bp[j];
    }
    __syncthreads();

    // steady loop: i = 1..128, 1 barrier/step
    for (int i = 1; i <= TOUT; ++i) {
        const int cur = i & 1, nxt = cur ^ 1;

        half8 af[4];
#pragma unroll
        for (int kc = 0; kc < 4; ++kc)
            af[kc] = *(const half8*)&als[cur][jl][NIN + kc * 32 + lg * 8];

        if (w < 4) {   // y_{i-1} = oW.h_{i-1} + ob (off the recurrence path)
            f32x4 ya = {oB, oB, oB, oB};
#pragma unroll
            for (int kc = 0; kc < 4; ++kc)
                ya = __builtin_amdgcn_mfma_f32_16x16x32_f16(af[kc], of[kc], ya, 0, 0, 0);
            const int tt = (i - 1) & (TCH - 1);
            const int j = w * 16 + jl;
#pragma unroll
            for (int r = 0; r < 4; ++r)
                ybuf[tt][lg * 4 + r][j] = (_Float16)ya[r];
        }

        if (i < TOUT) {
            f32x4 ac[4];
#pragma unroll
            for (int q = 0; q < 4; ++q) {
                f32x4 a = {bq[q], bq[q], bq[q], bq[q]};
#pragma unroll
                for (int kc = 0; kc < 4; ++kc)
                    a = __builtin_amdgcn_mfma_f32_16x16x32_f16(af[kc], wf[q][kc], a, 0, 0, 0);
                ac[q] = a;
            }
#pragma unroll
            for (int r = 0; r < 4; ++r) {
                const float ig = sigf(ac[0][r]);
                const float fg = sigf(ac[1][r]);
                const float gg = tanhfast(ac[2][r]);
                const float og = sigf(ac[3][r]);
                c[r] = fg * c[r] + ig * gg;
                const float hv = og * tanhfast(c[r]);
                als[nxt][lg * 4 + r][NIN + w * 16 + jl] = (_Float16)hv;
            }
        }
        __syncthreads();

        if ((i & (TCH - 1)) == 0) {
            const int t0 = i - TCH;
#pragma unroll
            for (int it = 0; it < 8; ++it) {
                const int slot = it * 512 + tid;
                const int pair = slot >> 2;
                const int tq   = slot & 3;
                const int row  = pair >> 6;
                const int j    = pair & 63;
                float4 v;
                v.x = (float)ybuf[tq * 4 + 0][row][j];
                v.y = (float)ybuf[tq * 4 + 1][row][j];
                v.z = (float)ybuf[tq * 4 + 2][row][j];
                v.w = (float)ybuf[tq * 4 + 3][row][j];
                *(float4*)(out + ((size_t)(b0 + row) * NOUT + j) * TOUT + t0 + tq * 4) = v;
            }
            __syncthreads();
        }
    }
}

extern "C" void kernel_launch(void* const* d_in, const int* in_sizes, int n_in,
                              void* d_out, int out_size, void* d_ws, size_t ws_size,
                              hipStream_t stream) {
    (void)in_sizes; (void)n_in; (void)out_size; (void)ws_size;
    const float* x    = (const float*)d_in[0];
    const float* eWih = (const float*)d_in[1];
    const float* eWhh = (const float*)d_in[2];
    const float* eb   = (const float*)d_in[3];
    const float* dWih = (const float*)d_in[4];
    const float* dWhh = (const float*)d_in[5];
    const float* db   = (const float*)d_in[6];
    const float* oW   = (const float*)d_in[7];
    const float* ob   = (const float*)d_in[8];

    char* ws = (char*)d_ws;
    _Float16* Wp  = (_Float16*)(ws);
    float*    bp  = (float*)(ws + 131072);
    _Float16* hws = (_Float16*)(ws + 262144);
    float*    cws = (float*)(ws + 786432);

    prep_wp   <<<129, 512, 0, stream>>>(dWih, dWhh, db, oW, ob, Wp, bp);
    enc_kernel<<<BATCHN / BT, 512, 0, stream>>>(x, eWih, eWhh, eb, hws, cws);
    dec_kernel<<<BATCHN / BT, 512, 0, stream>>>(dWhh, db, oW, ob, Wp, bp, hws, cws,
                                                (float*)d_out);
}